// Round 1
// baseline (1226.729 us; speedup 1.0000x reference)
//
#include <hip/hip_runtime.h>

// Problem constants (from reference): B=16, SP1=513, V=32000
#define CE_B   16
#define CE_SP1 513
#define CE_S   512      // SP1 - 1
#define CE_V   32000
#define CE_V4  (CE_V / 4)   // 8000 float4 per row
#define BLOCK  256

// ws layout: ws[0] = running nll sum (float), ws[1] = running count (float)

__global__ void ce_init(float* __restrict__ ws) {
    ws[0] = 0.0f;
    ws[1] = 0.0f;
}

__global__ __launch_bounds__(BLOCK) void ce_row(
        const float* __restrict__ logits,   // (B, SP1, V) fp32
        const int*   __restrict__ trg,      // (B, SP1) int32
        const int*   __restrict__ lengths,  // (B,) int32
        float*       __restrict__ ws) {

    const int row = blockIdx.x;        // 0 .. B*S-1
    const int b   = row >> 9;          // row / 512
    const int s   = row & (CE_S - 1);  // row % 512

    // mask = (s < lengths[b]) && (trg[b, s+1] != 0)
    const int tgt = trg[b * CE_SP1 + s + 1];
    const int len = lengths[b];
    if (s >= len || tgt == 0) return;  // skip: no HBM row fetch at all

    const float* __restrict__ x =
        logits + (size_t)(b * CE_SP1 + s + 1) * CE_V;
    const float4* __restrict__ x4 = (const float4*)x;

    const int t = threadIdx.x;

    // single-pass online softmax accumulation (per-thread)
    float m   = -__builtin_inff();
    float sum = 0.0f;

    for (int i = t; i < CE_V4; i += BLOCK) {
        float4 v = x4[i];
        float m4   = fmaxf(fmaxf(v.x, v.y), fmaxf(v.z, v.w));
        float mnew = fmaxf(m, m4);
        sum = sum * __expf(m - mnew)
            + __expf(v.x - mnew) + __expf(v.y - mnew)
            + __expf(v.z - mnew) + __expf(v.w - mnew);
        m = mnew;
    }

    // wave-level butterfly reduce of (m, sum) across 64 lanes
    #pragma unroll
    for (int off = 32; off > 0; off >>= 1) {
        float mo = __shfl_xor(m,   off, 64);
        float so = __shfl_xor(sum, off, 64);
        float mn = fmaxf(m, mo);
        sum = sum * __expf(m - mn) + so * __expf(mo - mn);
        m = mn;
    }

    // cross-wave combine via LDS (4 waves per block)
    __shared__ float sm[BLOCK / 64];
    __shared__ float ss[BLOCK / 64];
    const int wave = t >> 6;
    const int lane = t & 63;
    if (lane == 0) { sm[wave] = m; ss[wave] = sum; }
    __syncthreads();

    if (t == 0) {
        float M = sm[0];
        float Ssum = ss[0];
        #pragma unroll
        for (int w = 1; w < BLOCK / 64; ++w) {
            float mo = sm[w], so = ss[w];
            float mn = fmaxf(M, mo);
            Ssum = Ssum * __expf(M - mn) + so * __expf(mo - mn);
            M = mn;
        }
        const float lse = M + __logf(Ssum);
        const float nll = lse - x[tgt];
        atomicAdd(&ws[0], nll);
        atomicAdd(&ws[1], 1.0f);
    }
}

__global__ void ce_final(const float* __restrict__ ws,
                         float* __restrict__ out) {
    out[0] = ws[0] / fmaxf(ws[1], 1.0f);
}

extern "C" void kernel_launch(void* const* d_in, const int* in_sizes, int n_in,
                              void* d_out, int out_size, void* d_ws, size_t ws_size,
                              hipStream_t stream) {
    const float* logits  = (const float*)d_in[0];  // (16, 513, 32000) fp32
    const int*   trg     = (const int*)  d_in[1];  // (16, 513) int32
    const int*   lengths = (const int*)  d_in[2];  // (16,) int32
    float*       ws      = (float*)d_ws;
    float*       out     = (float*)d_out;

    ce_init <<<1, 1, 0, stream>>>(ws);
    ce_row  <<<CE_B * CE_S, BLOCK, 0, stream>>>(logits, trg, lengths, ws);
    ce_final<<<1, 1, 0, stream>>>(ws, out);
}